// Round 1
// baseline (842.233 us; speedup 1.0000x reference)
//
#include <hip/hip_runtime.h>

#define M_TOK 16384   // B*S = 8*2048
#define K_DIM 1024    // H
#define N_DIM 4096    // I

using i32x4 = __attribute__((ext_vector_type(4))) int;

// ---------- helpers ----------
__device__ __forceinline__ unsigned enc_f(float f) {
  unsigned b = __float_as_uint(f);
  return (b & 0x80000000u) ? ~b : (b | 0x80000000u);
}
__device__ __forceinline__ float dec_f(unsigned u) {
  unsigned b = (u & 0x80000000u) ? (u & 0x7FFFFFFFu) : ~u;
  return __uint_as_float(b);
}

#define GL2LDS16(g, s)                                                         \
  __builtin_amdgcn_global_load_lds(                                            \
      (const __attribute__((address_space(1))) void*)(g),                      \
      (__attribute__((address_space(3))) void*)(s), 16, 0, 0)

// IntGELU elementwise, literal f32 emulation of the reference.
// pa = (b_int(bias), bias_sf, b_g, c_g) ; pb.x = shift_int, pb.y = sf_out
__device__ __forceinline__ float gelu_val(int acc, float4 pa, float4 pb) {
  float oi = (float)acc + pa.x;      // out_int = einsum + b_int   (exact ints)
  float h  = oi * pa.y;              // quant_linear output
  float xi = h / pa.y;               // int_gelu: x_int = x / sf   (IEEE div)
  float sgn = (xi > 0.f) ? 1.f : ((xi < 0.f) ? -1.f : 0.f);
  float ab  = fminf(fabsf(xi), -pa.z);
  float tt  = ab + pa.z;
  float yi  = sgn * (tt * tt + pa.w);
  yi = floorf(yi * (1.0f / 16384.0f));   // floor(y / 2^14), exact pow2 scale
  float q = xi * (yi + pb.x);
  return q * pb.y;                   // * sf_out
}

// ---------- kernel 1: x -> int8 ----------
__global__ void k_prep_x(const float* __restrict__ x,
                         const float* __restrict__ sfp,
                         int* __restrict__ x8) {
  float sfin = sfp[0];
  int i = blockIdx.x * 256 + threadIdx.x;           // float4 index
  float4 v = ((const float4*)x)[i];
  int c0 = (int)rintf(v.x / sfin);
  int c1 = (int)rintf(v.y / sfin);
  int c2 = (int)rintf(v.z / sfin);
  int c3 = (int)rintf(v.w / sfin);
  x8[i] = (c0 & 0xFF) | ((c1 & 0xFF) << 8) | ((c2 & 0xFF) << 16)
        | ((c3 & 0xFF) << 24);
}

// ---------- kernel 2: weight quant + per-channel constants ----------
__global__ void k_prep_w(const float* __restrict__ W,
                         const float* __restrict__ bias,
                         const float* __restrict__ sfp,
                         int* __restrict__ w8,
                         float4* __restrict__ cA,
                         float4* __restrict__ cB,
                         unsigned* __restrict__ gmm) {
  const int o = blockIdx.x;
  const int t = threadIdx.x;
  float4 wv = ((const float4*)(W + (size_t)o * K_DIM))[t];   // 256*4 = 1024
  float vmn = fminf(fminf(wv.x, wv.y), fminf(wv.z, wv.w));
  float vmx = fmaxf(fmaxf(wv.x, wv.y), fmaxf(wv.z, wv.w));
#pragma unroll
  for (int off = 32; off; off >>= 1) {
    vmn = fminf(vmn, __shfl_down(vmn, off, 64));
    vmx = fmaxf(vmx, __shfl_down(vmx, off, 64));
  }
  __shared__ float sm[8];
  __shared__ float s_wsf;
  int lane = t & 63, wv_id = t >> 6;
  if (lane == 0) { sm[wv_id] = vmn; sm[4 + wv_id] = vmx; }
  __syncthreads();
  if (t == 0) {
    float mn = fminf(fminf(sm[0], sm[1]), fminf(sm[2], sm[3]));
    float mx = fmaxf(fmaxf(sm[4], sm[5]), fmaxf(sm[6], sm[7]));
    float wsf = fmaxf(fmaxf(fabsf(mn), fabsf(mx)), 1e-8f) / 127.0f;
    s_wsf = wsf;
    float sfin = sfp[0];
    float bsf  = wsf * sfin;                         // bias_sf
    float bint = rintf(bias[o] / bsf);               // b_int
    float sfe  = bsf / 1.4142f;                      // sf / GELU_K
    float bg   = floorf(-1.769f / sfe);              // gelu b_int
    const float C2F = (float)(1.0 / -0.2888);        // C2 computed in double
    float cg   = floorf(C2F / (sfe * sfe));          // gelu c_int
    float sfsig = sfe * sfe * (-0.2888f);
    sfsig = sfsig * 16384.0f;                        // * 2^14
    float shiftint = floorf(1.0f / sfsig);
    float sfout = bsf * sfsig / 2.0f;
    cA[o] = make_float4(bint, bsf, bg, cg);
    cB[o] = make_float4(shiftint, sfout, 0.0f, 0.0f);
    if (o == 0) { gmm[0] = 0xFFFFFFFFu; gmm[1] = 0u; }  // min-enc, max-enc
  }
  __syncthreads();
  float wsf = s_wsf;
  int q0 = (int)fminf(fmaxf(rintf(wv.x / wsf), -128.f), 127.f);
  int q1 = (int)fminf(fmaxf(rintf(wv.y / wsf), -128.f), 127.f);
  int q2 = (int)fminf(fmaxf(rintf(wv.z / wsf), -128.f), 127.f);
  int q3 = (int)fminf(fmaxf(rintf(wv.w / wsf), -128.f), 127.f);
  w8[(size_t)o * (K_DIM / 4) + t] =
      (q0 & 0xFF) | ((q1 & 0xFF) << 8) | ((q2 & 0xFF) << 16) | ((q3 & 0xFF) << 24);
}

// ---------- kernel 3/5: int8 GEMM + GELU (+minmax | +requant+store) --------
// 128x128 block tile, 4 waves (2x2), each wave 64x64 via 4x4 of 16x16x64 MFMA.
template <int MODE>
__global__ __launch_bounds__(256) void k_gemm(
    const signed char* __restrict__ A, const signed char* __restrict__ B,
    const float4* __restrict__ cA, const float4* __restrict__ cB,
    float* __restrict__ out, unsigned* __restrict__ gmm,
    const float* __restrict__ sfws) {
  __shared__ __align__(16) signed char As[128 * 64];
  __shared__ __align__(16) signed char Bs[128 * 64];
  const int t = threadIdx.x;
  const int lane = t & 63;
  const int w = t >> 6;
  const int wm = w >> 1, wn = w & 1;
  const int m0 = blockIdx.y * 128;
  const int n0 = blockIdx.x * 128;
  const signed char* Ag = A + (size_t)m0 * K_DIM;
  const signed char* Bg = B + (size_t)n0 * K_DIM;

  i32x4 acc[4][4] = {};

  // staging chunks: chunk c -> row c>>2, 16B slice (c&3)*16; thread t owns c=t, t+256
  const int c0 = t, c1 = t + 256;
  const int r0 = c0 >> 2, off0 = (c0 & 3) * 16;
  const int r1 = c1 >> 2, off1 = (c1 & 3) * 16;

  const i32x4* As4 = (const i32x4*)As;
  const i32x4* Bs4 = (const i32x4*)Bs;
  const int koff = lane >> 4;             // 16B chunk within the 64B K-row
  const int arow = wm * 64 + (lane & 15);
  const int brow = wn * 64 + (lane & 15);

  for (int kk = 0; kk < K_DIM; kk += 64) {
    __syncthreads();
    GL2LDS16(Ag + (size_t)r0 * K_DIM + kk + off0, As + c0 * 16);
    GL2LDS16(Ag + (size_t)r1 * K_DIM + kk + off1, As + c1 * 16);
    GL2LDS16(Bg + (size_t)r0 * K_DIM + kk + off0, Bs + c0 * 16);
    GL2LDS16(Bg + (size_t)r1 * K_DIM + kk + off1, Bs + c1 * 16);
    __syncthreads();

    i32x4 af[4], bf[4];
#pragma unroll
    for (int i = 0; i < 4; ++i) af[i] = As4[(arow + i * 16) * 4 + koff];
#pragma unroll
    for (int i = 0; i < 4; ++i) bf[i] = Bs4[(brow + i * 16) * 4 + koff];
#pragma unroll
    for (int mi = 0; mi < 4; ++mi)
#pragma unroll
      for (int ni = 0; ni < 4; ++ni)
        acc[mi][ni] = __builtin_amdgcn_mfma_i32_16x16x64_i8(
            af[mi], bf[ni], acc[mi][ni], 0, 0, 0);
  }

  // epilogue: C/D layout col = lane&15, row = (lane>>4)*4 + reg
  const int rowb = m0 + wm * 64 + (lane >> 4) * 4;
  const int colb = n0 + wn * 64 + (lane & 15);
  float vmin = 3.4e38f, vmax = -3.4e38f;
  float sf = (MODE == 1) ? sfws[0] : 0.0f;

#pragma unroll
  for (int ni = 0; ni < 4; ++ni) {
    const int col = colb + ni * 16;
    const float4 pa = cA[col];
    const float4 pb = cB[col];
#pragma unroll
    for (int mi = 0; mi < 4; ++mi) {
#pragma unroll
      for (int r = 0; r < 4; ++r) {
        float xg = gelu_val(acc[mi][ni][r], pa, pb);
        if (MODE == 0) {
          vmin = fminf(vmin, xg);
          vmax = fmaxf(vmax, xg);
        } else {
          float z  = rintf(xg / pb.y);                 // round(x / pre_sf)
          float rr = rintf(z * pb.z * pb.w);           // round(z*m_int*2^(e-31))
          rr = fminf(fmaxf(rr, -128.f), 127.f);        // clip after round
          out[(size_t)(rowb + mi * 16 + r) * N_DIM + col] = rr * sf;
        }
      }
    }
  }

  if (MODE == 0) {
#pragma unroll
    for (int off = 32; off; off >>= 1) {
      vmin = fminf(vmin, __shfl_down(vmin, off, 64));
      vmax = fmaxf(vmax, __shfl_down(vmax, off, 64));
    }
    if (lane == 0) {
      atomicMin(&gmm[0], enc_f(vmin));
      atomicMax(&gmm[1], enc_f(vmax));
    }
  }
}

// ---------- kernel 4: scalar sf + per-channel requant constants ----------
__global__ void k_scalar(const unsigned* __restrict__ gmm,
                         float4* __restrict__ cB,
                         float* __restrict__ sfws,
                         float* __restrict__ out_sf) {
  float mn = dec_f(gmm[0]);
  float mx = dec_f(gmm[1]);
  float sf = fmaxf(fmaxf(fabsf(mn), fabsf(mx)), 1e-8f) / 127.0f;
  int o = blockIdx.x * 256 + threadIdx.x;
  if (o == 0) { sfws[0] = sf; out_sf[0] = sf; }
  float4 cb = cB[o];
  int e;
  float mm = frexpf(cb.y / sf, &e);       // frexp(pre_sf / sf)
  cb.z = rintf(mm * 2147483648.0f);       // m_int = round(m * 2^31)
  cb.w = ldexpf(1.0f, e - 31);            // exact 2^(e-31)
  cB[o] = cb;
}

// ---------- launch ----------
extern "C" void kernel_launch(void* const* d_in, const int* in_sizes, int n_in,
                              void* d_out, int out_size, void* d_ws, size_t ws_size,
                              hipStream_t stream) {
  const float* x    = (const float*)d_in[0];
  const float* sfp  = (const float*)d_in[1];
  const float* W    = (const float*)d_in[2];
  const float* bias = (const float*)d_in[3];
  float* out = (float*)d_out;

  char* ws = (char*)d_ws;
  signed char* x8 = (signed char*)ws;                               // 16 MB
  signed char* w8 = (signed char*)(ws + (size_t)M_TOK * K_DIM);     // 4 MB
  char* tail = ws + (size_t)M_TOK * K_DIM + (size_t)N_DIM * K_DIM;
  float4* cA = (float4*)tail;                                       // 64 KB
  float4* cB = (float4*)(tail + (size_t)N_DIM * 16);                // 64 KB
  unsigned* gmm = (unsigned*)(tail + (size_t)N_DIM * 32);           // 8 B
  float* sfws = (float*)(tail + (size_t)N_DIM * 32 + 16);

  k_prep_x<<<(M_TOK * K_DIM / 4) / 256, 256, 0, stream>>>(x, sfp, (int*)x8);
  k_prep_w<<<N_DIM, 256, 0, stream>>>(W, bias, sfp, (int*)w8, cA, cB, gmm);
  k_gemm<0><<<dim3(N_DIM / 128, M_TOK / 128), 256, 0, stream>>>(
      x8, w8, cA, cB, out, gmm, sfws);
  k_scalar<<<N_DIM / 256, 256, 0, stream>>>(gmm, cB, sfws,
                                            out + (size_t)M_TOK * N_DIM);
  k_gemm<1><<<dim3(N_DIM / 128, M_TOK / 128), 256, 0, stream>>>(
      x8, w8, cA, cB, out, gmm, sfws);
}

// Round 2
// 827.120 us; speedup vs baseline: 1.0183x; 1.0183x over previous
//
#include <hip/hip_runtime.h>

#define M_TOK 16384   // B*S = 8*2048
#define K_DIM 1024    // H
#define N_DIM 4096    // I

using i32x4 = __attribute__((ext_vector_type(4))) int;

// ---------- helpers ----------
__device__ __forceinline__ unsigned enc_f(float f) {
  unsigned b = __float_as_uint(f);
  return (b & 0x80000000u) ? ~b : (b | 0x80000000u);
}
__device__ __forceinline__ float dec_f(unsigned u) {
  unsigned b = (u & 0x80000000u) ? (u & 0x7FFFFFFFu) : ~u;
  return __uint_as_float(b);
}

#define GL2LDS16(g, s)                                                         \
  __builtin_amdgcn_global_load_lds(                                            \
      (const __attribute__((address_space(1))) void*)(g),                      \
      (__attribute__((address_space(3))) void*)(s), 16, 0, 0)

// IntGELU elementwise, literal f32 emulation of the reference.
// pa = (b_int(bias), bias_sf, b_g, c_g) ; pb.x = shift_int, pb.y = sf_out
__device__ __forceinline__ float gelu_val(int acc, float4 pa, float4 pb) {
  float oi = (float)acc + pa.x;      // out_int = einsum + b_int   (exact ints)
  float h  = oi * pa.y;              // quant_linear output
  float xi = h / pa.y;               // int_gelu: x_int = x / sf   (IEEE div)
  float sgn = (xi > 0.f) ? 1.f : ((xi < 0.f) ? -1.f : 0.f);
  float ab  = fminf(fabsf(xi), -pa.z);
  float tt  = ab + pa.z;
  float yi  = sgn * (tt * tt + pa.w);
  yi = floorf(yi * (1.0f / 16384.0f));   // floor(y / 2^14), exact pow2 scale
  float q = xi * (yi + pb.x);
  return q * pb.y;                   // * sf_out
}

// ---------- kernel 1: x -> int8 ----------
__global__ void k_prep_x(const float* __restrict__ x,
                         const float* __restrict__ sfp,
                         int* __restrict__ x8) {
  float sfin = sfp[0];
  int i = blockIdx.x * 256 + threadIdx.x;           // float4 index
  float4 v = ((const float4*)x)[i];
  int c0 = (int)rintf(v.x / sfin);
  int c1 = (int)rintf(v.y / sfin);
  int c2 = (int)rintf(v.z / sfin);
  int c3 = (int)rintf(v.w / sfin);
  x8[i] = (c0 & 0xFF) | ((c1 & 0xFF) << 8) | ((c2 & 0xFF) << 16)
        | ((c3 & 0xFF) << 24);
}

// ---------- kernel 2: weight quant + per-channel constants ----------
__global__ void k_prep_w(const float* __restrict__ W,
                         const float* __restrict__ bias,
                         const float* __restrict__ sfp,
                         int* __restrict__ w8,
                         float4* __restrict__ cA,
                         float4* __restrict__ cB,
                         unsigned* __restrict__ gmm) {
  const int o = blockIdx.x;
  const int t = threadIdx.x;
  float4 wv = ((const float4*)(W + (size_t)o * K_DIM))[t];   // 256*4 = 1024
  float vmn = fminf(fminf(wv.x, wv.y), fminf(wv.z, wv.w));
  float vmx = fmaxf(fmaxf(wv.x, wv.y), fmaxf(wv.z, wv.w));
#pragma unroll
  for (int off = 32; off; off >>= 1) {
    vmn = fminf(vmn, __shfl_down(vmn, off, 64));
    vmx = fmaxf(vmx, __shfl_down(vmx, off, 64));
  }
  __shared__ float sm[8];
  __shared__ float s_wsf;
  int lane = t & 63, wv_id = t >> 6;
  if (lane == 0) { sm[wv_id] = vmn; sm[4 + wv_id] = vmx; }
  __syncthreads();
  if (t == 0) {
    float mn = fminf(fminf(sm[0], sm[1]), fminf(sm[2], sm[3]));
    float mx = fmaxf(fmaxf(sm[4], sm[5]), fmaxf(sm[6], sm[7]));
    float wsf = fmaxf(fmaxf(fabsf(mn), fabsf(mx)), 1e-8f) / 127.0f;
    s_wsf = wsf;
    float sfin = sfp[0];
    float bsf  = wsf * sfin;                         // bias_sf
    float bint = rintf(bias[o] / bsf);               // b_int
    float sfe  = bsf / 1.4142f;                      // sf / GELU_K
    float bg   = floorf(-1.769f / sfe);              // gelu b_int
    const float C2F = (float)(1.0 / -0.2888);        // C2 computed in double
    float cg   = floorf(C2F / (sfe * sfe));          // gelu c_int
    float sfsig = sfe * sfe * (-0.2888f);
    sfsig = sfsig * 16384.0f;                        // * 2^14
    float shiftint = floorf(1.0f / sfsig);
    float sfout = bsf * sfsig / 2.0f;
    cA[o] = make_float4(bint, bsf, bg, cg);
    cB[o] = make_float4(shiftint, sfout, 0.0f, 0.0f);
    if (o == 0) { gmm[0] = 0xFFFFFFFFu; gmm[1] = 0u; }  // min-enc, max-enc
  }
  __syncthreads();
  float wsf = s_wsf;
  int q0 = (int)fminf(fmaxf(rintf(wv.x / wsf), -128.f), 127.f);
  int q1 = (int)fminf(fmaxf(rintf(wv.y / wsf), -128.f), 127.f);
  int q2 = (int)fminf(fmaxf(rintf(wv.z / wsf), -128.f), 127.f);
  int q3 = (int)fminf(fmaxf(rintf(wv.w / wsf), -128.f), 127.f);
  w8[(size_t)o * (K_DIM / 4) + t] =
      (q0 & 0xFF) | ((q1 & 0xFF) << 8) | ((q2 & 0xFF) << 16) | ((q3 & 0xFF) << 24);
}

// ---------- kernel 3/5: int8 GEMM + GELU (+minmax | +requant+store) --------
// 128x128 block tile, 4 waves (2x2), each wave 64x64 via 4x4 of 16x16x64 MFMA.
// Double-buffered LDS (one barrier/iter) + XOR-swizzled chunk layout:
//   LDS chunk c (16B) of a tile buffer holds global (row = c>>2,
//   kslice s = ((c&3) - (c>>3)) & 3); i.e. stored column k' = (s + (row>>1))&3.
//   Read side: lane (m,koff) reads chunk row*4 + ((koff + (m>>1)) & 3)
//   -> every (row-parity, k') 4-bank group gets exactly 2 lanes = free 2-way.
template <int MODE>
__global__ __launch_bounds__(256) void k_gemm(
    const signed char* __restrict__ A, const signed char* __restrict__ B,
    const float4* __restrict__ cA, const float4* __restrict__ cB,
    float* __restrict__ out, unsigned* __restrict__ gmm,
    const float* __restrict__ sfws) {
  __shared__ __align__(16) signed char As[2][128 * 64];
  __shared__ __align__(16) signed char Bs[2][128 * 64];
  const int t = threadIdx.x;
  const int lane = t & 63;
  const int w = t >> 6;
  const int wm = w >> 1, wn = w & 1;
  const int m0 = blockIdx.y * 128;
  const int n0 = blockIdx.x * 128;
  const signed char* Ag = A + (size_t)m0 * K_DIM;
  const signed char* Bg = B + (size_t)n0 * K_DIM;

  i32x4 acc[4][4] = {};

  // staging: thread t owns chunks c0=t, c1=t+256 (LDS dest = wave-uniform
  // base + lane*16, global_load_lds-legal). Global source is swizzle-permuted.
  const int c0 = t, c1 = t + 256;
  const int r0 = c0 >> 2, s0 = ((c0 & 3) - (c0 >> 3)) & 3;
  const int r1 = c1 >> 2, s1 = ((c1 & 3) - (c1 >> 3)) & 3;
  const size_t ga0 = (size_t)r0 * K_DIM + s0 * 16;
  const size_t ga1 = (size_t)r1 * K_DIM + s1 * 16;

  // fragment read offsets (bytes) inside a tile buffer
  const int m = lane & 15, koff = lane >> 4;
  const int kprime = (koff + (m >> 1)) & 3;
  const int aoff = (wm * 64 + m) * 64 + kprime * 16;   // + i*1024 per frag
  const int boff = (wn * 64 + m) * 64 + kprime * 16;

  // prologue: stage k-slab 0 into buffer 0
  GL2LDS16(Ag + ga0, As[0] + c0 * 16);
  GL2LDS16(Ag + ga1, As[0] + c1 * 16);
  GL2LDS16(Bg + ga0, Bs[0] + c0 * 16);
  GL2LDS16(Bg + ga1, Bs[0] + c1 * 16);

  for (int it = 0; it < K_DIM / 64; ++it) {
    __syncthreads();   // drains vmcnt -> buf[it&1] ready; prev reads retired
    const int nb = (it + 1) & 1;
    if (it + 1 < K_DIM / 64) {
      const size_t kk = (size_t)(it + 1) * 64;
      GL2LDS16(Ag + kk + ga0, As[nb] + c0 * 16);
      GL2LDS16(Ag + kk + ga1, As[nb] + c1 * 16);
      GL2LDS16(Bg + kk + ga0, Bs[nb] + c0 * 16);
      GL2LDS16(Bg + kk + ga1, Bs[nb] + c1 * 16);
    }
    const signed char* ab = As[it & 1];
    const signed char* bb = Bs[it & 1];
    i32x4 af[4], bf[4];
#pragma unroll
    for (int i = 0; i < 4; ++i)
      af[i] = *(const i32x4*)(ab + aoff + i * 1024);
#pragma unroll
    for (int i = 0; i < 4; ++i)
      bf[i] = *(const i32x4*)(bb + boff + i * 1024);
#pragma unroll
    for (int mi = 0; mi < 4; ++mi)
#pragma unroll
      for (int ni = 0; ni < 4; ++ni)
        acc[mi][ni] = __builtin_amdgcn_mfma_i32_16x16x64_i8(
            af[mi], bf[ni], acc[mi][ni], 0, 0, 0);
  }

  // epilogue: C/D layout col = lane&15, row = (lane>>4)*4 + reg
  const int rowb = m0 + wm * 64 + (lane >> 4) * 4;
  const int colb = n0 + wn * 64 + (lane & 15);
  float vmin = 3.4e38f, vmax = -3.4e38f;
  float sf = (MODE == 1) ? sfws[0] : 0.0f;

#pragma unroll
  for (int ni = 0; ni < 4; ++ni) {
    const int col = colb + ni * 16;
    const float4 pa = cA[col];
    const float4 pb = cB[col];
#pragma unroll
    for (int mi = 0; mi < 4; ++mi) {
#pragma unroll
      for (int r = 0; r < 4; ++r) {
        float xg = gelu_val(acc[mi][ni][r], pa, pb);
        if (MODE == 0) {
          vmin = fminf(vmin, xg);
          vmax = fmaxf(vmax, xg);
        } else {
          float z  = rintf(xg / pb.y);                 // round(x / pre_sf)
          float rr = rintf(z * pb.z * pb.w);           // round(z*m_int*2^(e-31))
          rr = fminf(fmaxf(rr, -128.f), 127.f);        // clip after round
          out[(size_t)(rowb + mi * 16 + r) * N_DIM + col] = rr * sf;
        }
      }
    }
  }

  if (MODE == 0) {
#pragma unroll
    for (int off = 32; off; off >>= 1) {
      vmin = fminf(vmin, __shfl_down(vmin, off, 64));
      vmax = fmaxf(vmax, __shfl_down(vmax, off, 64));
    }
    if (lane == 0) {
      atomicMin(&gmm[0], enc_f(vmin));
      atomicMax(&gmm[1], enc_f(vmax));
    }
  }
}

// ---------- kernel 4: scalar sf + per-channel requant constants ----------
__global__ void k_scalar(const unsigned* __restrict__ gmm,
                         float4* __restrict__ cB,
                         float* __restrict__ sfws,
                         float* __restrict__ out_sf) {
  float mn = dec_f(gmm[0]);
  float mx = dec_f(gmm[1]);
  float sf = fmaxf(fmaxf(fabsf(mn), fabsf(mx)), 1e-8f) / 127.0f;
  int o = blockIdx.x * 256 + threadIdx.x;
  if (o == 0) { sfws[0] = sf; out_sf[0] = sf; }
  float4 cb = cB[o];
  int e;
  float mm = frexpf(cb.y / sf, &e);       // frexp(pre_sf / sf)
  cb.z = rintf(mm * 2147483648.0f);       // m_int = round(m * 2^31)
  cb.w = ldexpf(1.0f, e - 31);            // exact 2^(e-31)
  cB[o] = cb;
}

// ---------- launch ----------
extern "C" void kernel_launch(void* const* d_in, const int* in_sizes, int n_in,
                              void* d_out, int out_size, void* d_ws, size_t ws_size,
                              hipStream_t stream) {
  const float* x    = (const float*)d_in[0];
  const float* sfp  = (const float*)d_in[1];
  const float* W    = (const float*)d_in[2];
  const float* bias = (const float*)d_in[3];
  float* out = (float*)d_out;

  char* ws = (char*)d_ws;
  signed char* x8 = (signed char*)ws;                               // 16 MB
  signed char* w8 = (signed char*)(ws + (size_t)M_TOK * K_DIM);     // 4 MB
  char* tail = ws + (size_t)M_TOK * K_DIM + (size_t)N_DIM * K_DIM;
  float4* cA = (float4*)tail;                                       // 64 KB
  float4* cB = (float4*)(tail + (size_t)N_DIM * 16);                // 64 KB
  unsigned* gmm = (unsigned*)(tail + (size_t)N_DIM * 32);           // 8 B
  float* sfws = (float*)(tail + (size_t)N_DIM * 32 + 16);

  k_prep_x<<<(M_TOK * K_DIM / 4) / 256, 256, 0, stream>>>(x, sfp, (int*)x8);
  k_prep_w<<<N_DIM, 256, 0, stream>>>(W, bias, sfp, (int*)w8, cA, cB, gmm);
  k_gemm<0><<<dim3(N_DIM / 128, M_TOK / 128), 256, 0, stream>>>(
      x8, w8, cA, cB, out, gmm, sfws);
  k_scalar<<<N_DIM / 256, 256, 0, stream>>>(gmm, cB, sfws,
                                            out + (size_t)M_TOK * N_DIM);
  k_gemm<1><<<dim3(N_DIM / 128, M_TOK / 128), 256, 0, stream>>>(
      x8, w8, cA, cB, out, gmm, sfws);
}